// Round 3
// baseline (8773.260 us; speedup 1.0000x reference)
//
#include <hip/hip_runtime.h>

// ---------------------------------------------------------------------------
// BN -> patchify -> embed -> all-pairs MLP_LN (correl, U[i]+V[j] split) ->
// xcorr pyramid -> interleave -> appc -> xpath pyramid -> 4-layer head.
// All fp32.  E=100, HID=150, P=256, B=4.
//
// v3: weights staged global->LDS in K-chunks (read via 16-lane broadcast),
// x read directly from global (16 lanes share one address -> 1 transaction),
// 37KB LDS/block -> 4 blocks/CU, in-register LayerNorm epilogue.
// ---------------------------------------------------------------------------

#define RR 32          // rows per block
#define HT_S 152       // ht row stride (K2 padded to 152, cols 150/151 = 0)
#define W1_S 28        // phase-1 weight slab row stride (Kc=24)
#define W2_S 44        // phase-2 weight slab row stride (Kc=40/32)
#define WBUF_FLOATS 4400   // max(150*28, 100*44)

// ---- phase 2: (rows x 150) @ w2^T(100x150) + b2 -> LayerNorm -> store ----
// thread (a=tid&15, b=tid>>4): outputs e = a+16i (i<7, e<100), rows b, b+16
__device__ __forceinline__ void phase2_ln(
    float* wbuf, const float* ht, int vrows,
    const float* __restrict__ w2, const float* __restrict__ b2,
    const float* __restrict__ gg, const float* __restrict__ bb,
    float* __restrict__ out, long row0)
{
  const int tid = threadIdx.x;
  const int a = tid & 15;
  const int b = tid >> 4;
  float acc0[7], acc1[7];
#pragma unroll
  for (int i = 0; i < 7; ++i) { acc0[i] = 0.f; acc1[i] = 0.f; }
  int woff[7];
#pragma unroll
  for (int i = 0; i < 7; ++i) {
    int e = a + 16 * i;
    woff[i] = (e < 100 ? e : 0) * W2_S;
  }
  // K2 = 152 in 4 chunks: 40,40,40,32
  for (int c = 0; c < 4; ++c) {
    const int k0 = c * 40;
    const int kc = (c < 3) ? 40 : 32;
    __syncthreads();
    const int nf = 100 * kc;
    for (int idx = tid; idx < nf; idx += 256) {
      int r = idx / kc, cc = idx - r * kc;
      int k = k0 + cc;
      wbuf[r * W2_S + cc] = (k < 150) ? w2[r * 150 + k] : 0.f;
    }
    __syncthreads();
    const int n4 = kc >> 2;
    const float* h0p = ht + b * HT_S + k0;
    const float* h1p = ht + (b + 16) * HT_S + k0;
    for (int k4 = 0; k4 < n4; ++k4) {
      float4 h0 = *reinterpret_cast<const float4*>(h0p + 4 * k4);
      float4 h1 = *reinterpret_cast<const float4*>(h1p + 4 * k4);
#pragma unroll
      for (int i = 0; i < 7; ++i) {
        float4 w = *reinterpret_cast<const float4*>(&wbuf[woff[i] + 4 * k4]);
        acc0[i] += h0.x * w.x; acc0[i] += h0.y * w.y;
        acc0[i] += h0.z * w.z; acc0[i] += h0.w * w.w;
        acc1[i] += h1.x * w.x; acc1[i] += h1.y * w.y;
        acc1[i] += h1.z * w.z; acc1[i] += h1.w * w.w;
      }
    }
  }
  // + bias, then in-register LayerNorm across the 16 a-lanes
  float s0 = 0.f, s1 = 0.f;
#pragma unroll
  for (int i = 0; i < 7; ++i) {
    int e = a + 16 * i;
    if (e < 100) {
      float bv = b2[e];
      acc0[i] += bv; acc1[i] += bv;
      s0 += acc0[i]; s1 += acc1[i];
    }
  }
#pragma unroll
  for (int m = 8; m; m >>= 1) { s0 += __shfl_xor(s0, m, 16); s1 += __shfl_xor(s1, m, 16); }
  float mu0 = s0 * 0.01f, mu1 = s1 * 0.01f;
  float v0 = 0.f, v1 = 0.f;
#pragma unroll
  for (int i = 0; i < 7; ++i) {
    int e = a + 16 * i;
    if (e < 100) {
      float d0 = acc0[i] - mu0, d1 = acc1[i] - mu1;
      v0 += d0 * d0; v1 += d1 * d1;
    }
  }
#pragma unroll
  for (int m = 8; m; m >>= 1) { v0 += __shfl_xor(v0, m, 16); v1 += __shfl_xor(v1, m, 16); }
  float rs0 = rsqrtf(v0 * 0.01f + 1e-5f);
  float rs1 = rsqrtf(v1 * 0.01f + 1e-5f);
  bool ok0 = b < vrows, ok1 = (b + 16) < vrows;
  float* o0 = out + (row0 + b) * 100;
  float* o1 = out + (row0 + b + 16) * 100;
#pragma unroll
  for (int i = 0; i < 7; ++i) {
    int e = a + 16 * i;
    if (e < 100) {
      float ge = gg[e], bee = bb[e];
      if (ok0) o0[e] = (acc0[i] - mu0) * rs0 * ge + bee;
      if (ok1) o1[e] = (acc1[i] - mu1) * rs1 * ge + bee;
    }
  }
}

// ---- generic merge: rows of 200 -> Linear(150)+ReLU -> Linear(100) -> LN ----
__global__ __launch_bounds__(256, 4) void mlp_merge_kernel(
    const float* __restrict__ in, float* __restrict__ out,
    const float* __restrict__ w1, const float* __restrict__ b1,
    const float* __restrict__ w2, const float* __restrict__ b2,
    const float* __restrict__ gg, const float* __restrict__ bb,
    int nrows)
{
  __shared__ __align__(16) float ht[RR * HT_S];
  __shared__ __align__(16) float wbuf[WBUF_FLOATS];
  const int tid = threadIdx.x;
  const int a = tid & 15;
  const int b = tid >> 4;
  const long row0 = (long)blockIdx.x * RR;
  const int vrows = min(RR, (int)(nrows - row0));
  const int r0 = (b < vrows) ? b : 0;
  const int r1 = ((b + 16) < vrows) ? (b + 16) : 0;
  const float* xr0 = in + (row0 + r0) * 200;
  const float* xr1 = in + (row0 + r1) * 200;
  int woff[10];
#pragma unroll
  for (int i = 0; i < 10; ++i) { int t = a + 16 * i; woff[i] = (t < 150 ? t : 0) * W1_S; }
  float acc0[10], acc1[10];
#pragma unroll
  for (int i = 0; i < 10; ++i) { acc0[i] = 0.f; acc1[i] = 0.f; }

  // phase 1: K1 = 200 in 9 chunks: 8x24 + 8
  for (int c = 0; c < 9; ++c) {
    const int k0 = c * 24;
    const int kc = (c < 8) ? 24 : 8;
    const int cpr = kc >> 2;          // float4s per slab row
    __syncthreads();
    const int nf4 = 150 * cpr;
    for (int idx = tid; idx < nf4; idx += 256) {
      int r = idx / cpr, cc = idx - r * cpr;
      *reinterpret_cast<float4*>(&wbuf[r * W1_S + 4 * cc]) =
          *reinterpret_cast<const float4*>(w1 + r * 200 + k0 + 4 * cc);
    }
    __syncthreads();
    for (int k4 = 0; k4 < cpr; ++k4) {
      float4 x0 = *reinterpret_cast<const float4*>(xr0 + k0 + 4 * k4);
      float4 x1 = *reinterpret_cast<const float4*>(xr1 + k0 + 4 * k4);
#pragma unroll
      for (int i = 0; i < 10; ++i) {
        float4 w = *reinterpret_cast<const float4*>(&wbuf[woff[i] + 4 * k4]);
        acc0[i] += x0.x * w.x; acc0[i] += x0.y * w.y;
        acc0[i] += x0.z * w.z; acc0[i] += x0.w * w.w;
        acc1[i] += x1.x * w.x; acc1[i] += x1.y * w.y;
        acc1[i] += x1.z * w.z; acc1[i] += x1.w * w.w;
      }
    }
  }
  __syncthreads();
  // write ht (ReLU + bias), zero-pad cols 150/151
#pragma unroll
  for (int i = 0; i < 10; ++i) {
    int t = a + 16 * i;
    if (t < 150) {
      float bt = b1[t];
      ht[b * HT_S + t] = fmaxf(acc0[i] + bt, 0.f);
      ht[(b + 16) * HT_S + t] = fmaxf(acc1[i] + bt, 0.f);
    } else if (t < 152) {
      ht[b * HT_S + t] = 0.f;
      ht[(b + 16) * HT_S + t] = 0.f;
    }
  }
  phase2_ln(wbuf, ht, vrows, w2, b2, gg, bb, out, row0);
}

// ---- correl: ht[j][t] = relu(U[i][t]+V[j][t]+b1[t]) then chunked phase2+LN ----
__global__ __launch_bounds__(256, 4) void correl_kernel(
    const float* __restrict__ U, const float* __restrict__ V,
    const float* __restrict__ b1,
    const float* __restrict__ w2, const float* __restrict__ b2,
    const float* __restrict__ gg, const float* __restrict__ bb,
    float* __restrict__ out)
{
  __shared__ __align__(16) float ht[RR * HT_S];
  __shared__ __align__(16) float wbuf[WBUF_FLOATS];
  __shared__ float u_lds[152];
  const int tid = threadIdx.x;
  const int bx = blockIdx.x;         // 8192 = 1024 bi * 8 j-chunks
  const int bi = bx >> 3;            // b*256 + i
  const int j0 = (bx & 7) * RR;
  const int bnum = bi >> 8;
  if (tid < 150) u_lds[tid] = U[(long)bi * 150 + tid] + b1[tid];
  __syncthreads();
  const float* vb = V + ((long)(bnum * 256 + j0)) * 150;
  for (int idx = tid; idx < RR * 150; idx += 256) {
    int j = idx / 150, t = idx - j * 150;
    ht[j * HT_S + t] = fmaxf(u_lds[t] + vb[idx], 0.f);
  }
  if (tid < 64) ht[(tid >> 1) * HT_S + 150 + (tid & 1)] = 0.f;  // zero pad
  phase2_ln(wbuf, ht, RR, w2, b2, gg, bb, out, (long)bi * 256 + j0);
}

// ---- BatchNorm2d (training) per-channel stats, folded to scale/shift ----
__global__ void bn_stats_kernel(const float* __restrict__ x,
    const float* __restrict__ bn_w, const float* __restrict__ bn_b,
    float* __restrict__ stats)
{
  __shared__ float s_sum[256], s_sq[256];
  const int c = blockIdx.x;
  const int tid = threadIdx.x;
  float s = 0.f, q = 0.f;
  for (int idx = tid; idx < 4 * 65536; idx += 256) {
    int b = idx >> 16, hw = idx & 65535;
    float v = x[(((long)(b * 3 + c)) << 16) + hw];
    s += v; q += v * v;
  }
  s_sum[tid] = s; s_sq[tid] = q;
  __syncthreads();
  for (int off = 128; off > 0; off >>= 1) {
    if (tid < off) { s_sum[tid] += s_sum[tid + off]; s_sq[tid] += s_sq[tid + off]; }
    __syncthreads();
  }
  if (tid == 0) {
    const float n = 262144.f;
    float mu = s_sum[0] / n;
    float var = s_sq[0] / n - mu * mu;   // biased var, matches ref
    float rs = rsqrtf(var + 1e-5f);
    float scale = rs * bn_w[c];
    stats[c] = scale;
    stats[4 + c] = bn_b[c] - mu * scale;
  }
}

// ---- patchify + patch-embedding + pos ----
__global__ __launch_bounds__(256) void embed_kernel(
    const float* __restrict__ x, const float* __restrict__ stats,
    const float* __restrict__ pe_w, const float* __restrict__ pe_b,
    const float* __restrict__ pos, float* __restrict__ emb)
{
  __shared__ __align__(16) float patch[768];
  const int tid = threadIdx.x;
  const int bp = blockIdx.x;            // b*256 + p
  const int b = bp >> 8, p = bp & 255;
  const int nhi = p >> 4, nwi = p & 15;
  for (int i = tid; i < 768; i += 256) {
    int ph = i / 48, rem = i % 48;
    int pw = rem / 3, c = rem % 3;
    float v = x[(((long)(b * 3 + c)) * 256 + (nhi * 16 + ph)) * 256 + (nwi * 16 + pw)];
    patch[i] = v * stats[c] + stats[4 + c];
  }
  __syncthreads();
  if (tid < 100) {
    const float* w = pe_w + tid * 768;
    float a0 = 0.f, a1 = 0.f, a2 = 0.f, a3 = 0.f;
    for (int k = 0; k < 768; k += 4) {
      float4 p4 = *reinterpret_cast<const float4*>(patch + k);
      float4 w4 = *reinterpret_cast<const float4*>(w + k);
      a0 += p4.x * w4.x; a1 += p4.y * w4.y;
      a2 += p4.z * w4.z; a3 += p4.w * w4.w;
    }
    emb[(long)bp * 100 + tid] = a0 + a1 + a2 + a3 + pe_b[tid] + pos[p * 100 + tid];
  }
}

// ---- U = W1[:, :100] @ emb, V = W1[:, 100:] @ emb ----
__global__ __launch_bounds__(256) void uv_kernel(
    const float* __restrict__ emb, const float* __restrict__ w1,
    float* __restrict__ U, float* __restrict__ V)
{
  __shared__ __align__(16) float e_lds[100];
  const int tid = threadIdx.x;
  const int bp = blockIdx.x;
  if (tid < 100) e_lds[tid] = emb[(long)bp * 100 + tid];
  __syncthreads();
  if (tid < 150) {
    const float* w = w1 + tid * 200;
    float a0 = 0.f, a1 = 0.f, c0 = 0.f, c1 = 0.f;
    for (int k = 0; k < 100; k += 2) {
      float2 e2 = *reinterpret_cast<const float2*>(e_lds + k);
      a0 += e2.x * w[k];       a1 += e2.y * w[k + 1];
      c0 += e2.x * w[100 + k]; c1 += e2.y * w[100 + k + 1];
    }
    U[(long)bp * 150 + tid] = a0 + a1;
    V[(long)bp * 150 + tid] = c0 + c1;
  }
}

// ---- interleave emb & cc into ec rows of 200 ----
__global__ void ec_kernel(const float* __restrict__ emb,
    const float* __restrict__ cc, float* __restrict__ ec)
{
  int g = blockIdx.x * 256 + threadIdx.x;
  if (g < 1024 * 100) {
    int o = g / 100, e = g % 100;
    ec[(long)o * 200 + 2 * e] = emb[g];
    ec[(long)o * 200 + 2 * e + 1] = cc[g];
  }
}

// ---- final 4-layer MLP head, one block per batch element ----
__global__ __launch_bounds__(256) void head_kernel(
    const float* __restrict__ cp,
    const float* __restrict__ w1, const float* __restrict__ b1,
    const float* __restrict__ w2, const float* __restrict__ b2,
    const float* __restrict__ w3, const float* __restrict__ b3,
    const float* __restrict__ w4, const float* __restrict__ b4,
    float* __restrict__ out)
{
  __shared__ float a0[400], a1[200], a2[100], a3[50];
  const int b = blockIdx.x, tid = threadIdx.x;
  for (int i = tid; i < 400; i += 256) a0[i] = cp[b * 400 + i];
  __syncthreads();
  if (tid < 200) {
    float s = b1[tid];
    const float* w = w1 + tid * 400;
    for (int k = 0; k < 400; ++k) s += a0[k] * w[k];
    a1[tid] = fmaxf(s, 0.f);
  }
  __syncthreads();
  if (tid < 100) {
    float s = b2[tid];
    const float* w = w2 + tid * 200;
    for (int k = 0; k < 200; ++k) s += a1[k] * w[k];
    a2[tid] = fmaxf(s, 0.f);
  }
  __syncthreads();
  if (tid < 50) {
    float s = b3[tid];
    const float* w = w3 + tid * 100;
    for (int k = 0; k < 100; ++k) s += a2[k] * w[k];
    a3[tid] = fmaxf(s, 0.f);
  }
  __syncthreads();
  if (tid < 5) {
    float s = b4[tid];
    const float* w = w4 + tid * 50;
    for (int k = 0; k < 50; ++k) s += a3[k] * w[k];
    out[b * 5 + tid] = s;
  }
}

extern "C" void kernel_launch(void* const* d_in, const int* in_sizes, int n_in,
                              void* d_out, int out_size, void* d_ws, size_t ws_size,
                              hipStream_t stream)
{
  const float* x    = (const float*)d_in[0];
  const float* bn_w = (const float*)d_in[1];
  const float* bn_b = (const float*)d_in[2];
  const float* pe_w = (const float*)d_in[3];
  const float* pe_b = (const float*)d_in[4];
  const float* pos  = (const float*)d_in[5];
  const float* cw1 = (const float*)d_in[6];
  const float* cb1 = (const float*)d_in[7];
  const float* cw2 = (const float*)d_in[8];
  const float* cb2 = (const float*)d_in[9];
  const float* cg  = (const float*)d_in[10];
  const float* cbe = (const float*)d_in[11];
  const float* xw1 = (const float*)d_in[12];
  const float* xb1 = (const float*)d_in[13];
  const float* xw2 = (const float*)d_in[14];
  const float* xb2 = (const float*)d_in[15];
  const float* xg  = (const float*)d_in[16];
  const float* xbe = (const float*)d_in[17];
  const float* aw1 = (const float*)d_in[18];
  const float* ab1 = (const float*)d_in[19];
  const float* aw2 = (const float*)d_in[20];
  const float* ab2 = (const float*)d_in[21];
  const float* ag  = (const float*)d_in[22];
  const float* abe = (const float*)d_in[23];
  const float* pw1 = (const float*)d_in[24];
  const float* pb1 = (const float*)d_in[25];
  const float* pw2 = (const float*)d_in[26];
  const float* pb2 = (const float*)d_in[27];
  const float* pg  = (const float*)d_in[28];
  const float* pbe = (const float*)d_in[29];
  const float* h1w = (const float*)d_in[30];
  const float* h1b = (const float*)d_in[31];
  const float* h2w = (const float*)d_in[32];
  const float* h2b = (const float*)d_in[33];
  const float* h3w = (const float*)d_in[34];
  const float* h3b = (const float*)d_in[35];
  const float* h4w = (const float*)d_in[36];
  const float* h4b = (const float*)d_in[37];

  // workspace layout (floats)
  const size_t OFF_STATS = 0;                       // 16
  const size_t OFF_EMB   = 16;                      // 1024*100
  const size_t OFF_U     = OFF_EMB + 102400;        // 1024*150
  const size_t OFF_V     = OFF_U + 153600;          // 1024*150
  const size_t OFF_EC    = OFF_V + 153600;          // 1024*200
  const size_t OFF_A     = OFF_EC + 204800;         // 262144*100
  const size_t OFF_B     = OFF_A + 26214400;        // 131072*100
  const size_t NEED = (OFF_B + 13107200) * sizeof(float);
  if (ws_size < NEED) return;

  float* ws    = (float*)d_ws;
  float* stats = ws + OFF_STATS;
  float* emb   = ws + OFF_EMB;
  float* U     = ws + OFF_U;
  float* V     = ws + OFF_V;
  float* ec    = ws + OFF_EC;
  float* A     = ws + OFF_A;
  float* B     = ws + OFF_B;

  bn_stats_kernel<<<3, 256, 0, stream>>>(x, bn_w, bn_b, stats);
  embed_kernel<<<1024, 256, 0, stream>>>(x, stats, pe_w, pe_b, pos, emb);
  uv_kernel<<<1024, 256, 0, stream>>>(emb, cw1, U, V);
  correl_kernel<<<8192, 256, 0, stream>>>(U, V, cb1, cw2, cb2, cg, cbe, A);

  // xcorr pyramid: d 256 -> 1 (8 merge steps), rows = 1024 * half
  float* cur = A; float* nxt = B;
  int half = 128;
  for (int s = 0; s < 8; ++s) {
    int nrows = 1024 * half;
    mlp_merge_kernel<<<(nrows + RR - 1) / RR, 256, 0, stream>>>(
        cur, nxt, xw1, xb1, xw2, xb2, xg, xbe, nrows);
    float* t = cur; cur = nxt; nxt = t;
    half >>= 1;
  }
  // cc now in `cur` (== A), 1024 rows of 100

  ec_kernel<<<(102400 + 255) / 256, 256, 0, stream>>>(emb, cur, ec);
  mlp_merge_kernel<<<(1024 + RR - 1) / RR, 256, 0, stream>>>(
      ec, B, aw1, ab1, aw2, ab2, ag, abe, 1024);

  // xpath pyramid: p 256 -> 4 (6 merge steps), rows = 4 * half
  cur = B; nxt = A;
  half = 128;
  for (int s = 0; s < 6; ++s) {
    int nrows = 4 * half;
    mlp_merge_kernel<<<(nrows + RR - 1) / RR, 256, 0, stream>>>(
        cur, nxt, pw1, pb1, pw2, pb2, pg, pbe, nrows);
    float* t = cur; cur = nxt; nxt = t;
    half >>= 1;
  }
  // cp now in `cur` (== B), shape (4, 400)

  head_kernel<<<4, 256, 0, stream>>>(cur, h1w, h1b, h2w, h2b, h3w, h3b, h4w, h4b,
                                     (float*)d_out);
}

// Round 4
// 1638.181 us; speedup vs baseline: 5.3555x; 5.3555x over previous
//
#include <hip/hip_runtime.h>

// ---------------------------------------------------------------------------
// BN -> patchify -> embed -> all-pairs MLP_LN (correl, U[i]+V[j] split) ->
// xcorr pyramid -> interleave -> appc -> xpath pyramid -> 4-layer head.
// All fp32.  E=100, HID=150, P=256, B=4.
//
// v4: 64 rows/block, 4 rows/thread (160 FMA per 10 LDS reads in phase 1),
// w1 staged in LDS quarters (48/48/48/56), w2 in halves (76/76, K padded
// to 152), ~13 barriers/block each covering >=12 k4 iters. 75KB LDS ->
// 2 blocks/CU (8 waves/CU), VGPR capped at 256.
// ---------------------------------------------------------------------------

#define RR 64          // rows per block
#define HT_S 152       // ht row stride (K2 padded to 152; cols 150/151 = 0)
#define W1_S 60        // w1 quarter slab row stride (chunks 48/48/48/56)
#define W2_S 76        // w2 half slab row stride (chunks 76/76)

// ---- phase 2: (rows x 152) @ w2slab + b2 -> LayerNorm -> store ----
// thread (a=tid&15, b=tid>>4): outputs e = a+16i (i<7, e<100), rows b+16j (j<4)
__device__ __forceinline__ void phase2_ln(
    float* __restrict__ wbuf, const float* __restrict__ ht, int vrows,
    const float* __restrict__ w2, const float* __restrict__ b2,
    const float* __restrict__ gg, const float* __restrict__ bb,
    float* __restrict__ out, long row0)
{
  const int tid = threadIdx.x;
  const int a = tid & 15;
  const int b = tid >> 4;
  float acc[7][4];
#pragma unroll
  for (int i = 0; i < 7; ++i)
#pragma unroll
    for (int j = 0; j < 4; ++j) acc[i][j] = 0.f;
  int woff[7];
#pragma unroll
  for (int i = 0; i < 7; ++i) { int e = a + 16 * i; woff[i] = (e < 100 ? e : 0) * W2_S; }

  for (int h = 0; h < 2; ++h) {
    __syncthreads();   // h=0: ht ready & wbuf free; h=1: all done reading half 0
    // stage w2 half h: 100 rows x 38 float2 (zeros for k>=150)
    for (int idx = tid; idx < 100 * 38; idx += 256) {
      int r = idx / 38, c = idx - r * 38;
      int k = 76 * h + 2 * c;
      float2 v;
      if (k < 150) v = *reinterpret_cast<const float2*>(w2 + r * 150 + k);
      else         v = make_float2(0.f, 0.f);
      *reinterpret_cast<float2*>(&wbuf[r * W2_S + 2 * c]) = v;
    }
    __syncthreads();
    const int kb = 76 * h;
    for (int k4 = 0; k4 < 19; ++k4) {
      float4 hv[4];
#pragma unroll
      for (int j = 0; j < 4; ++j)
        hv[j] = *reinterpret_cast<const float4*>(&ht[(b + 16 * j) * HT_S + kb + 4 * k4]);
#pragma unroll
      for (int i = 0; i < 7; ++i) {
        float4 w = *reinterpret_cast<const float4*>(&wbuf[woff[i] + 4 * k4]);
#pragma unroll
        for (int j = 0; j < 4; ++j) {
          acc[i][j] += hv[j].x * w.x; acc[i][j] += hv[j].y * w.y;
          acc[i][j] += hv[j].z * w.z; acc[i][j] += hv[j].w * w.w;
        }
      }
    }
  }
  // + bias, in-register LayerNorm across the 16 a-lanes
  float s[4] = {0.f, 0.f, 0.f, 0.f};
#pragma unroll
  for (int i = 0; i < 7; ++i) {
    int e = a + 16 * i;
    if (e < 100) {
      float bv = b2[e];
#pragma unroll
      for (int j = 0; j < 4; ++j) { acc[i][j] += bv; s[j] += acc[i][j]; }
    }
  }
#pragma unroll
  for (int m = 8; m; m >>= 1)
#pragma unroll
    for (int j = 0; j < 4; ++j) s[j] += __shfl_xor(s[j], m, 16);
  float mu[4], vv[4] = {0.f, 0.f, 0.f, 0.f};
#pragma unroll
  for (int j = 0; j < 4; ++j) mu[j] = s[j] * 0.01f;
#pragma unroll
  for (int i = 0; i < 7; ++i) {
    int e = a + 16 * i;
    if (e < 100) {
#pragma unroll
      for (int j = 0; j < 4; ++j) { float d = acc[i][j] - mu[j]; vv[j] += d * d; }
    }
  }
#pragma unroll
  for (int m = 8; m; m >>= 1)
#pragma unroll
    for (int j = 0; j < 4; ++j) vv[j] += __shfl_xor(vv[j], m, 16);
  float rs[4];
#pragma unroll
  for (int j = 0; j < 4; ++j) rs[j] = rsqrtf(vv[j] * 0.01f + 1e-5f);
#pragma unroll
  for (int j = 0; j < 4; ++j) {
    int r = b + 16 * j;
    if (r < vrows) {
      float* o = out + (row0 + r) * 100;
#pragma unroll
      for (int i = 0; i < 7; ++i) {
        int e = a + 16 * i;
        if (e < 100) o[e] = (acc[i][j] - mu[j]) * rs[j] * gg[e] + bb[e];
      }
    }
  }
}

// ---- generic merge: rows of 200 -> Linear(150)+ReLU -> Linear(100) -> LN ----
__global__ __launch_bounds__(256, 2) void mlp_merge_kernel(
    const float* __restrict__ in, float* __restrict__ out,
    const float* __restrict__ w1, const float* __restrict__ b1,
    const float* __restrict__ w2, const float* __restrict__ b2,
    const float* __restrict__ gg, const float* __restrict__ bb,
    int nrows)
{
  __shared__ __align__(16) float wbuf[150 * W1_S];   // 36000 B; reused for w2 slab (7600 fl)
  __shared__ __align__(16) float ht[RR * HT_S];      // 38912 B
  const int tid = threadIdx.x;
  const int a = tid & 15;
  const int b = tid >> 4;
  const long row0 = (long)blockIdx.x * RR;
  const int vrows = min(RR, (int)(nrows - row0));
  const float* xr[4];
#pragma unroll
  for (int j = 0; j < 4; ++j) {
    int r = b + 16 * j;
    xr[j] = in + (row0 + (r < vrows ? r : 0)) * 200;
  }
  int woff[10];
#pragma unroll
  for (int i = 0; i < 10; ++i) { int t = a + 16 * i; woff[i] = (t < 150 ? t : 0) * W1_S; }
  float acc[10][4];
#pragma unroll
  for (int i = 0; i < 10; ++i)
#pragma unroll
    for (int j = 0; j < 4; ++j) acc[i][j] = 0.f;

  // phase 1: K=200 in quarters 48/48/48/56 (all float4, 16B-aligned starts)
  const int k0s[4] = {0, 48, 96, 144};
  for (int q = 0; q < 4; ++q) {
    const int k0 = k0s[q];
    const int nk4 = (q < 3) ? 12 : 14;
    __syncthreads();                         // previous slab fully consumed
    for (int idx = tid; idx < 150 * nk4; idx += 256) {
      int r = idx / nk4, c = idx - r * nk4;
      *reinterpret_cast<float4*>(&wbuf[r * W1_S + 4 * c]) =
          *reinterpret_cast<const float4*>(w1 + r * 200 + k0 + 4 * c);
    }
    __syncthreads();
    for (int k4 = 0; k4 < nk4; ++k4) {
      float4 xv[4];
#pragma unroll
      for (int j = 0; j < 4; ++j)
        xv[j] = *reinterpret_cast<const float4*>(xr[j] + k0 + 4 * k4);
#pragma unroll
      for (int i = 0; i < 10; ++i) {
        float4 w = *reinterpret_cast<const float4*>(&wbuf[woff[i] + 4 * k4]);
#pragma unroll
        for (int j = 0; j < 4; ++j) {
          acc[i][j] += xv[j].x * w.x; acc[i][j] += xv[j].y * w.y;
          acc[i][j] += xv[j].z * w.z; acc[i][j] += xv[j].w * w.w;
        }
      }
    }
  }
  // ReLU + bias -> ht (phase2_ln's first barrier makes these visible)
#pragma unroll
  for (int i = 0; i < 10; ++i) {
    int t = a + 16 * i;
    if (t < 150) {
      float bt = b1[t];
#pragma unroll
      for (int j = 0; j < 4; ++j)
        ht[(b + 16 * j) * HT_S + t] = fmaxf(acc[i][j] + bt, 0.f);
    } else if (t < 152) {
#pragma unroll
      for (int j = 0; j < 4; ++j)
        ht[(b + 16 * j) * HT_S + t] = 0.f;
    }
  }
  phase2_ln(wbuf, ht, vrows, w2, b2, gg, bb, out, row0);
}

// ---- correl: ht[j][t] = relu(U[i][t]+V[j][t]+b1[t]) then phase2+LN ----
__global__ __launch_bounds__(256, 2) void correl_kernel(
    const float* __restrict__ U, const float* __restrict__ V,
    const float* __restrict__ b1,
    const float* __restrict__ w2, const float* __restrict__ b2,
    const float* __restrict__ gg, const float* __restrict__ bb,
    float* __restrict__ out)
{
  __shared__ __align__(16) float wbuf[100 * W2_S];   // 30400 B
  __shared__ __align__(16) float ht[RR * HT_S];      // 38912 B
  __shared__ float u_lds[152];
  const int tid = threadIdx.x;
  const int bx = blockIdx.x;           // 4096 = 1024 bi * 4 j-chunks
  const int bi = bx >> 2;              // b*256 + i
  const int j0 = (bx & 3) * RR;
  const int bimg = bi >> 8;
  if (tid < 150) u_lds[tid] = U[(long)bi * 150 + tid] + b1[tid];
  __syncthreads();
  const float2* vb2 = reinterpret_cast<const float2*>(V + ((long)(bimg * 256 + j0)) * 150);
  for (int idx = tid; idx < 4800; idx += 256) {     // 64 rows x 75 float2
    int j = idx / 75, c = idx - j * 75;
    float2 v = vb2[idx];
    ht[j * HT_S + 2 * c]     = fmaxf(u_lds[2 * c]     + v.x, 0.f);
    ht[j * HT_S + 2 * c + 1] = fmaxf(u_lds[2 * c + 1] + v.y, 0.f);
  }
  if (tid < 128) ht[(tid >> 1) * HT_S + 150 + (tid & 1)] = 0.f;
  phase2_ln(wbuf, ht, RR, w2, b2, gg, bb, out, (long)bi * 256 + j0);
}

// ---- BatchNorm2d (training) per-channel stats, folded to scale/shift ----
__global__ void bn_stats_kernel(const float* __restrict__ x,
    const float* __restrict__ bn_w, const float* __restrict__ bn_b,
    float* __restrict__ stats)
{
  __shared__ float s_sum[256], s_sq[256];
  const int c = blockIdx.x;
  const int tid = threadIdx.x;
  float s = 0.f, q = 0.f;
  for (int idx = tid; idx < 4 * 65536; idx += 256) {
    int b = idx >> 16, hw = idx & 65535;
    float v = x[(((long)(b * 3 + c)) << 16) + hw];
    s += v; q += v * v;
  }
  s_sum[tid] = s; s_sq[tid] = q;
  __syncthreads();
  for (int off = 128; off > 0; off >>= 1) {
    if (tid < off) { s_sum[tid] += s_sum[tid + off]; s_sq[tid] += s_sq[tid + off]; }
    __syncthreads();
  }
  if (tid == 0) {
    const float n = 262144.f;
    float mu = s_sum[0] / n;
    float var = s_sq[0] / n - mu * mu;   // biased var, matches ref
    float rs = rsqrtf(var + 1e-5f);
    float scale = rs * bn_w[c];
    stats[c] = scale;
    stats[4 + c] = bn_b[c] - mu * scale;
  }
}

// ---- patchify + patch-embedding + pos ----
__global__ __launch_bounds__(256) void embed_kernel(
    const float* __restrict__ x, const float* __restrict__ stats,
    const float* __restrict__ pe_w, const float* __restrict__ pe_b,
    const float* __restrict__ pos, float* __restrict__ emb)
{
  __shared__ __align__(16) float patch[768];
  const int tid = threadIdx.x;
  const int bp = blockIdx.x;            // b*256 + p
  const int b = bp >> 8, p = bp & 255;
  const int nhi = p >> 4, nwi = p & 15;
  for (int i = tid; i < 768; i += 256) {
    int ph = i / 48, rem = i % 48;
    int pw = rem / 3, c = rem % 3;
    float v = x[(((long)(b * 3 + c)) * 256 + (nhi * 16 + ph)) * 256 + (nwi * 16 + pw)];
    patch[i] = v * stats[c] + stats[4 + c];
  }
  __syncthreads();
  if (tid < 100) {
    const float* w = pe_w + tid * 768;
    float a0 = 0.f, a1 = 0.f, a2 = 0.f, a3 = 0.f;
    for (int k = 0; k < 768; k += 4) {
      float4 p4 = *reinterpret_cast<const float4*>(patch + k);
      float4 w4 = *reinterpret_cast<const float4*>(w + k);
      a0 += p4.x * w4.x; a1 += p4.y * w4.y;
      a2 += p4.z * w4.z; a3 += p4.w * w4.w;
    }
    emb[(long)bp * 100 + tid] = a0 + a1 + a2 + a3 + pe_b[tid] + pos[p * 100 + tid];
  }
}

// ---- U = W1[:, :100] @ emb, V = W1[:, 100:] @ emb ----
__global__ __launch_bounds__(256) void uv_kernel(
    const float* __restrict__ emb, const float* __restrict__ w1,
    float* __restrict__ U, float* __restrict__ V)
{
  __shared__ __align__(16) float e_lds[100];
  const int tid = threadIdx.x;
  const int bp = blockIdx.x;
  if (tid < 100) e_lds[tid] = emb[(long)bp * 100 + tid];
  __syncthreads();
  if (tid < 150) {
    const float* w = w1 + tid * 200;
    float a0 = 0.f, a1 = 0.f, c0 = 0.f, c1 = 0.f;
    for (int k = 0; k < 100; k += 2) {
      float2 e2 = *reinterpret_cast<const float2*>(e_lds + k);
      a0 += e2.x * w[k];       a1 += e2.y * w[k + 1];
      c0 += e2.x * w[100 + k]; c1 += e2.y * w[100 + k + 1];
    }
    U[(long)bp * 150 + tid] = a0 + a1;
    V[(long)bp * 150 + tid] = c0 + c1;
  }
}

// ---- interleave emb & cc into ec rows of 200 ----
__global__ void ec_kernel(const float* __restrict__ emb,
    const float* __restrict__ cc, float* __restrict__ ec)
{
  int g = blockIdx.x * 256 + threadIdx.x;
  if (g < 1024 * 100) {
    int o = g / 100, e = g % 100;
    ec[(long)o * 200 + 2 * e] = emb[g];
    ec[(long)o * 200 + 2 * e + 1] = cc[g];
  }
}

// ---- final 4-layer MLP head, one block per batch element ----
__global__ __launch_bounds__(256) void head_kernel(
    const float* __restrict__ cp,
    const float* __restrict__ w1, const float* __restrict__ b1,
    const float* __restrict__ w2, const float* __restrict__ b2,
    const float* __restrict__ w3, const float* __restrict__ b3,
    const float* __restrict__ w4, const float* __restrict__ b4,
    float* __restrict__ out)
{
  __shared__ float a0[400], a1[200], a2[100], a3[50];
  const int b = blockIdx.x, tid = threadIdx.x;
  for (int i = tid; i < 400; i += 256) a0[i] = cp[b * 400 + i];
  __syncthreads();
  if (tid < 200) {
    float s = b1[tid];
    const float* w = w1 + tid * 400;
    for (int k = 0; k < 400; ++k) s += a0[k] * w[k];
    a1[tid] = fmaxf(s, 0.f);
  }
  __syncthreads();
  if (tid < 100) {
    float s = b2[tid];
    const float* w = w2 + tid * 200;
    for (int k = 0; k < 200; ++k) s += a1[k] * w[k];
    a2[tid] = fmaxf(s, 0.f);
  }
  __syncthreads();
  if (tid < 50) {
    float s = b3[tid];
    const float* w = w3 + tid * 100;
    for (int k = 0; k < 100; ++k) s += a2[k] * w[k];
    a3[tid] = fmaxf(s, 0.f);
  }
  __syncthreads();
  if (tid < 5) {
    float s = b4[tid];
    const float* w = w4 + tid * 50;
    for (int k = 0; k < 50; ++k) s += a3[k] * w[k];
    out[b * 5 + tid] = s;
  }
}

extern "C" void kernel_launch(void* const* d_in, const int* in_sizes, int n_in,
                              void* d_out, int out_size, void* d_ws, size_t ws_size,
                              hipStream_t stream)
{
  const float* x    = (const float*)d_in[0];
  const float* bn_w = (const float*)d_in[1];
  const float* bn_b = (const float*)d_in[2];
  const float* pe_w = (const float*)d_in[3];
  const float* pe_b = (const float*)d_in[4];
  const float* pos  = (const float*)d_in[5];
  const float* cw1 = (const float*)d_in[6];
  const float* cb1 = (const float*)d_in[7];
  const float* cw2 = (const float*)d_in[8];
  const float* cb2 = (const float*)d_in[9];
  const float* cg  = (const float*)d_in[10];
  const float* cbe = (const float*)d_in[11];
  const float* xw1 = (const float*)d_in[12];
  const float* xb1 = (const float*)d_in[13];
  const float* xw2 = (const float*)d_in[14];
  const float* xb2 = (const float*)d_in[15];
  const float* xg  = (const float*)d_in[16];
  const float* xbe = (const float*)d_in[17];
  const float* aw1 = (const float*)d_in[18];
  const float* ab1 = (const float*)d_in[19];
  const float* aw2 = (const float*)d_in[20];
  const float* ab2 = (const float*)d_in[21];
  const float* ag  = (const float*)d_in[22];
  const float* abe = (const float*)d_in[23];
  const float* pw1 = (const float*)d_in[24];
  const float* pb1 = (const float*)d_in[25];
  const float* pw2 = (const float*)d_in[26];
  const float* pb2 = (const float*)d_in[27];
  const float* pg  = (const float*)d_in[28];
  const float* pbe = (const float*)d_in[29];
  const float* h1w = (const float*)d_in[30];
  const float* h1b = (const float*)d_in[31];
  const float* h2w = (const float*)d_in[32];
  const float* h2b = (const float*)d_in[33];
  const float* h3w = (const float*)d_in[34];
  const float* h3b = (const float*)d_in[35];
  const float* h4w = (const float*)d_in[36];
  const float* h4b = (const float*)d_in[37];

  // workspace layout (floats)
  const size_t OFF_STATS = 0;                       // 16
  const size_t OFF_EMB   = 16;                      // 1024*100
  const size_t OFF_U     = OFF_EMB + 102400;        // 1024*150
  const size_t OFF_V     = OFF_U + 153600;          // 1024*150
  const size_t OFF_EC    = OFF_V + 153600;          // 1024*200
  const size_t OFF_A     = OFF_EC + 204800;         // 262144*100
  const size_t OFF_B     = OFF_A + 26214400;        // 131072*100
  const size_t NEED = (OFF_B + 13107200) * sizeof(float);
  if (ws_size < NEED) return;

  float* ws    = (float*)d_ws;
  float* stats = ws + OFF_STATS;
  float* emb   = ws + OFF_EMB;
  float* U     = ws + OFF_U;
  float* V     = ws + OFF_V;
  float* ec    = ws + OFF_EC;
  float* A     = ws + OFF_A;
  float* B     = ws + OFF_B;

  bn_stats_kernel<<<3, 256, 0, stream>>>(x, bn_w, bn_b, stats);
  embed_kernel<<<1024, 256, 0, stream>>>(x, stats, pe_w, pe_b, pos, emb);
  uv_kernel<<<1024, 256, 0, stream>>>(emb, cw1, U, V);
  correl_kernel<<<4096, 256, 0, stream>>>(U, V, cb1, cw2, cb2, cg, cbe, A);

  // xcorr pyramid: d 256 -> 1 (8 merge steps), rows = 1024 * half
  float* cur = A; float* nxt = B;
  int half = 128;
  for (int s = 0; s < 8; ++s) {
    int nrows = 1024 * half;
    mlp_merge_kernel<<<(nrows + RR - 1) / RR, 256, 0, stream>>>(
        cur, nxt, xw1, xb1, xw2, xb2, xg, xbe, nrows);
    float* t = cur; cur = nxt; nxt = t;
    half >>= 1;
  }
  // cc now in `cur` (== A), 1024 rows of 100

  ec_kernel<<<(102400 + 255) / 256, 256, 0, stream>>>(emb, cur, ec);
  mlp_merge_kernel<<<(1024 + RR - 1) / RR, 256, 0, stream>>>(
      ec, B, aw1, ab1, aw2, ab2, ag, abe, 1024);

  // xpath pyramid: p 256 -> 4 (6 merge steps), rows = 4 * half
  cur = B; nxt = A;
  half = 128;
  for (int s = 0; s < 6; ++s) {
    int nrows = 4 * half;
    mlp_merge_kernel<<<(nrows + RR - 1) / RR, 256, 0, stream>>>(
        cur, nxt, pw1, pb1, pw2, pb2, pg, pbe, nrows);
    float* t = cur; cur = nxt; nxt = t;
    half >>= 1;
  }
  // cp now in `cur` (== B), shape (4, 400)

  head_kernel<<<4, 256, 0, stream>>>(cur, h1w, h1b, h2w, h2b, h3w, h3b, h4w, h4b,
                                     (float*)d_out);
}

// Round 5
// 1346.747 us; speedup vs baseline: 6.5144x; 1.2164x over previous
//
#include <hip/hip_runtime.h>

// ---------------------------------------------------------------------------
// BN -> patchify -> embed -> all-pairs MLP_LN (correl, U[i]+V[j] split) ->
// xcorr pyramid -> interleave -> appc -> xpath pyramid -> 4-layer head.
// All fp32.  E=100, HID=150, P=256, B=4.
//
// v5: v4 + two-stage BatchNorm stats (192-block partial reduce + finalize)
// replacing the 3-block serial reduction that was 25% of total runtime.
// ---------------------------------------------------------------------------

#define RR 64          // rows per block
#define HT_S 152       // ht row stride (K2 padded to 152; cols 150/151 = 0)
#define W1_S 60        // w1 quarter slab row stride (chunks 48/48/48/56)
#define W2_S 76        // w2 half slab row stride (chunks 76/76)

// ---- phase 2: (rows x 152) @ w2slab + b2 -> LayerNorm -> store ----
// thread (a=tid&15, b=tid>>4): outputs e = a+16i (i<7, e<100), rows b+16j (j<4)
__device__ __forceinline__ void phase2_ln(
    float* __restrict__ wbuf, const float* __restrict__ ht, int vrows,
    const float* __restrict__ w2, const float* __restrict__ b2,
    const float* __restrict__ gg, const float* __restrict__ bb,
    float* __restrict__ out, long row0)
{
  const int tid = threadIdx.x;
  const int a = tid & 15;
  const int b = tid >> 4;
  float acc[7][4];
#pragma unroll
  for (int i = 0; i < 7; ++i)
#pragma unroll
    for (int j = 0; j < 4; ++j) acc[i][j] = 0.f;
  int woff[7];
#pragma unroll
  for (int i = 0; i < 7; ++i) { int e = a + 16 * i; woff[i] = (e < 100 ? e : 0) * W2_S; }

  for (int h = 0; h < 2; ++h) {
    __syncthreads();   // h=0: ht ready & wbuf free; h=1: all done reading half 0
    // stage w2 half h: 100 rows x 38 float2 (zeros for k>=150)
    for (int idx = tid; idx < 100 * 38; idx += 256) {
      int r = idx / 38, c = idx - r * 38;
      int k = 76 * h + 2 * c;
      float2 v;
      if (k < 150) v = *reinterpret_cast<const float2*>(w2 + r * 150 + k);
      else         v = make_float2(0.f, 0.f);
      *reinterpret_cast<float2*>(&wbuf[r * W2_S + 2 * c]) = v;
    }
    __syncthreads();
    const int kb = 76 * h;
    for (int k4 = 0; k4 < 19; ++k4) {
      float4 hv[4];
#pragma unroll
      for (int j = 0; j < 4; ++j)
        hv[j] = *reinterpret_cast<const float4*>(&ht[(b + 16 * j) * HT_S + kb + 4 * k4]);
#pragma unroll
      for (int i = 0; i < 7; ++i) {
        float4 w = *reinterpret_cast<const float4*>(&wbuf[woff[i] + 4 * k4]);
#pragma unroll
        for (int j = 0; j < 4; ++j) {
          acc[i][j] += hv[j].x * w.x; acc[i][j] += hv[j].y * w.y;
          acc[i][j] += hv[j].z * w.z; acc[i][j] += hv[j].w * w.w;
        }
      }
    }
  }
  // + bias, in-register LayerNorm across the 16 a-lanes
  float s[4] = {0.f, 0.f, 0.f, 0.f};
#pragma unroll
  for (int i = 0; i < 7; ++i) {
    int e = a + 16 * i;
    if (e < 100) {
      float bv = b2[e];
#pragma unroll
      for (int j = 0; j < 4; ++j) { acc[i][j] += bv; s[j] += acc[i][j]; }
    }
  }
#pragma unroll
  for (int m = 8; m; m >>= 1)
#pragma unroll
    for (int j = 0; j < 4; ++j) s[j] += __shfl_xor(s[j], m, 16);
  float mu[4], vv[4] = {0.f, 0.f, 0.f, 0.f};
#pragma unroll
  for (int j = 0; j < 4; ++j) mu[j] = s[j] * 0.01f;
#pragma unroll
  for (int i = 0; i < 7; ++i) {
    int e = a + 16 * i;
    if (e < 100) {
#pragma unroll
      for (int j = 0; j < 4; ++j) { float d = acc[i][j] - mu[j]; vv[j] += d * d; }
    }
  }
#pragma unroll
  for (int m = 8; m; m >>= 1)
#pragma unroll
    for (int j = 0; j < 4; ++j) vv[j] += __shfl_xor(vv[j], m, 16);
  float rs[4];
#pragma unroll
  for (int j = 0; j < 4; ++j) rs[j] = rsqrtf(vv[j] * 0.01f + 1e-5f);
#pragma unroll
  for (int j = 0; j < 4; ++j) {
    int r = b + 16 * j;
    if (r < vrows) {
      float* o = out + (row0 + r) * 100;
#pragma unroll
      for (int i = 0; i < 7; ++i) {
        int e = a + 16 * i;
        if (e < 100) o[e] = (acc[i][j] - mu[j]) * rs[j] * gg[e] + bb[e];
      }
    }
  }
}

// ---- generic merge: rows of 200 -> Linear(150)+ReLU -> Linear(100) -> LN ----
__global__ __launch_bounds__(256, 2) void mlp_merge_kernel(
    const float* __restrict__ in, float* __restrict__ out,
    const float* __restrict__ w1, const float* __restrict__ b1,
    const float* __restrict__ w2, const float* __restrict__ b2,
    const float* __restrict__ gg, const float* __restrict__ bb,
    int nrows)
{
  __shared__ __align__(16) float wbuf[150 * W1_S];   // 36000 B; reused for w2 slab (7600 fl)
  __shared__ __align__(16) float ht[RR * HT_S];      // 38912 B
  const int tid = threadIdx.x;
  const int a = tid & 15;
  const int b = tid >> 4;
  const long row0 = (long)blockIdx.x * RR;
  const int vrows = min(RR, (int)(nrows - row0));
  const float* xr[4];
#pragma unroll
  for (int j = 0; j < 4; ++j) {
    int r = b + 16 * j;
    xr[j] = in + (row0 + (r < vrows ? r : 0)) * 200;
  }
  int woff[10];
#pragma unroll
  for (int i = 0; i < 10; ++i) { int t = a + 16 * i; woff[i] = (t < 150 ? t : 0) * W1_S; }
  float acc[10][4];
#pragma unroll
  for (int i = 0; i < 10; ++i)
#pragma unroll
    for (int j = 0; j < 4; ++j) acc[i][j] = 0.f;

  // phase 1: K=200 in quarters 48/48/48/56 (all float4, 16B-aligned starts)
  const int k0s[4] = {0, 48, 96, 144};
  for (int q = 0; q < 4; ++q) {
    const int k0 = k0s[q];
    const int nk4 = (q < 3) ? 12 : 14;
    __syncthreads();                         // previous slab fully consumed
    for (int idx = tid; idx < 150 * nk4; idx += 256) {
      int r = idx / nk4, c = idx - r * nk4;
      *reinterpret_cast<float4*>(&wbuf[r * W1_S + 4 * c]) =
          *reinterpret_cast<const float4*>(w1 + r * 200 + k0 + 4 * c);
    }
    __syncthreads();
    for (int k4 = 0; k4 < nk4; ++k4) {
      float4 xv[4];
#pragma unroll
      for (int j = 0; j < 4; ++j)
        xv[j] = *reinterpret_cast<const float4*>(xr[j] + k0 + 4 * k4);
#pragma unroll
      for (int i = 0; i < 10; ++i) {
        float4 w = *reinterpret_cast<const float4*>(&wbuf[woff[i] + 4 * k4]);
#pragma unroll
        for (int j = 0; j < 4; ++j) {
          acc[i][j] += xv[j].x * w.x; acc[i][j] += xv[j].y * w.y;
          acc[i][j] += xv[j].z * w.z; acc[i][j] += xv[j].w * w.w;
        }
      }
    }
  }
  // ReLU + bias -> ht (phase2_ln's first barrier makes these visible)
#pragma unroll
  for (int i = 0; i < 10; ++i) {
    int t = a + 16 * i;
    if (t < 150) {
      float bt = b1[t];
#pragma unroll
      for (int j = 0; j < 4; ++j)
        ht[(b + 16 * j) * HT_S + t] = fmaxf(acc[i][j] + bt, 0.f);
    } else if (t < 152) {
#pragma unroll
      for (int j = 0; j < 4; ++j)
        ht[(b + 16 * j) * HT_S + t] = 0.f;
    }
  }
  phase2_ln(wbuf, ht, vrows, w2, b2, gg, bb, out, row0);
}

// ---- correl: ht[j][t] = relu(U[i][t]+V[j][t]+b1[t]) then phase2+LN ----
__global__ __launch_bounds__(256, 2) void correl_kernel(
    const float* __restrict__ U, const float* __restrict__ V,
    const float* __restrict__ b1,
    const float* __restrict__ w2, const float* __restrict__ b2,
    const float* __restrict__ gg, const float* __restrict__ bb,
    float* __restrict__ out)
{
  __shared__ __align__(16) float wbuf[100 * W2_S];   // 30400 B
  __shared__ __align__(16) float ht[RR * HT_S];      // 38912 B
  __shared__ float u_lds[152];
  const int tid = threadIdx.x;
  const int bx = blockIdx.x;           // 4096 = 1024 bi * 4 j-chunks
  const int bi = bx >> 2;              // b*256 + i
  const int j0 = (bx & 3) * RR;
  const int bimg = bi >> 8;
  if (tid < 150) u_lds[tid] = U[(long)bi * 150 + tid] + b1[tid];
  __syncthreads();
  const float2* vb2 = reinterpret_cast<const float2*>(V + ((long)(bimg * 256 + j0)) * 150);
  for (int idx = tid; idx < 4800; idx += 256) {     // 64 rows x 75 float2
    int j = idx / 75, c = idx - j * 75;
    float2 v = vb2[idx];
    ht[j * HT_S + 2 * c]     = fmaxf(u_lds[2 * c]     + v.x, 0.f);
    ht[j * HT_S + 2 * c + 1] = fmaxf(u_lds[2 * c + 1] + v.y, 0.f);
  }
  if (tid < 128) ht[(tid >> 1) * HT_S + 150 + (tid & 1)] = 0.f;
  phase2_ln(wbuf, ht, RR, w2, b2, gg, bb, out, (long)bi * 256 + j0);
}

// ---- BatchNorm2d stats, two-stage: partial (3ch x 64 slices) + finalize ----
__global__ __launch_bounds__(256) void bn_partial_kernel(
    const float* __restrict__ x, float* __restrict__ part)
{
  __shared__ float s_sum[256], s_sq[256];
  const int c = blockIdx.x >> 6;        // channel
  const int s = blockIdx.x & 63;        // slice within channel
  const int tid = threadIdx.x;
  // per-channel logical length 4*65536; slice = 4096 elems, fully inside one b
  const int L = s << 12;                // logical start
  const int b = L >> 16, hw = L & 65535;
  const float4* p4 = reinterpret_cast<const float4*>(
      x + (((long)(b * 3 + c)) << 16) + hw);
  float sum = 0.f, sq = 0.f;
#pragma unroll
  for (int i = 0; i < 4; ++i) {
    float4 v = p4[tid + 256 * i];
    sum += v.x + v.y + v.z + v.w;
    sq += v.x * v.x + v.y * v.y + v.z * v.z + v.w * v.w;
  }
  s_sum[tid] = sum; s_sq[tid] = sq;
  __syncthreads();
  for (int off = 128; off > 0; off >>= 1) {
    if (tid < off) { s_sum[tid] += s_sum[tid + off]; s_sq[tid] += s_sq[tid + off]; }
    __syncthreads();
  }
  if (tid == 0) {
    part[2 * blockIdx.x] = s_sum[0];
    part[2 * blockIdx.x + 1] = s_sq[0];
  }
}

__global__ void bn_finalize_kernel(const float* __restrict__ part,
    const float* __restrict__ bn_w, const float* __restrict__ bn_b,
    float* __restrict__ stats)
{
  const int c = threadIdx.x;
  if (c < 3) {
    float sum = 0.f, sq = 0.f;
    for (int s = 0; s < 64; ++s) {
      sum += part[2 * (c * 64 + s)];
      sq += part[2 * (c * 64 + s) + 1];
    }
    const float n = 262144.f;
    float mu = sum / n;
    float var = sq / n - mu * mu;        // biased var, matches ref
    float rs = rsqrtf(var + 1e-5f);
    float scale = rs * bn_w[c];
    stats[c] = scale;
    stats[4 + c] = bn_b[c] - mu * scale;
  }
}

// ---- patchify + patch-embedding + pos ----
__global__ __launch_bounds__(256) void embed_kernel(
    const float* __restrict__ x, const float* __restrict__ stats,
    const float* __restrict__ pe_w, const float* __restrict__ pe_b,
    const float* __restrict__ pos, float* __restrict__ emb)
{
  __shared__ __align__(16) float patch[768];
  const int tid = threadIdx.x;
  const int bp = blockIdx.x;            // b*256 + p
  const int b = bp >> 8, p = bp & 255;
  const int nhi = p >> 4, nwi = p & 15;
  for (int i = tid; i < 768; i += 256) {
    int ph = i / 48, rem = i % 48;
    int pw = rem / 3, c = rem % 3;
    float v = x[(((long)(b * 3 + c)) * 256 + (nhi * 16 + ph)) * 256 + (nwi * 16 + pw)];
    patch[i] = v * stats[c] + stats[4 + c];
  }
  __syncthreads();
  if (tid < 100) {
    const float* w = pe_w + tid * 768;
    float a0 = 0.f, a1 = 0.f, a2 = 0.f, a3 = 0.f;
    for (int k = 0; k < 768; k += 4) {
      float4 p4 = *reinterpret_cast<const float4*>(patch + k);
      float4 w4 = *reinterpret_cast<const float4*>(w + k);
      a0 += p4.x * w4.x; a1 += p4.y * w4.y;
      a2 += p4.z * w4.z; a3 += p4.w * w4.w;
    }
    emb[(long)bp * 100 + tid] = a0 + a1 + a2 + a3 + pe_b[tid] + pos[p * 100 + tid];
  }
}

// ---- U = W1[:, :100] @ emb, V = W1[:, 100:] @ emb ----
__global__ __launch_bounds__(256) void uv_kernel(
    const float* __restrict__ emb, const float* __restrict__ w1,
    float* __restrict__ U, float* __restrict__ V)
{
  __shared__ __align__(16) float e_lds[100];
  const int tid = threadIdx.x;
  const int bp = blockIdx.x;
  if (tid < 100) e_lds[tid] = emb[(long)bp * 100 + tid];
  __syncthreads();
  if (tid < 150) {
    const float* w = w1 + tid * 200;
    float a0 = 0.f, a1 = 0.f, c0 = 0.f, c1 = 0.f;
    for (int k = 0; k < 100; k += 2) {
      float2 e2 = *reinterpret_cast<const float2*>(e_lds + k);
      a0 += e2.x * w[k];       a1 += e2.y * w[k + 1];
      c0 += e2.x * w[100 + k]; c1 += e2.y * w[100 + k + 1];
    }
    U[(long)bp * 150 + tid] = a0 + a1;
    V[(long)bp * 150 + tid] = c0 + c1;
  }
}

// ---- interleave emb & cc into ec rows of 200 ----
__global__ void ec_kernel(const float* __restrict__ emb,
    const float* __restrict__ cc, float* __restrict__ ec)
{
  int g = blockIdx.x * 256 + threadIdx.x;
  if (g < 1024 * 100) {
    int o = g / 100, e = g % 100;
    ec[(long)o * 200 + 2 * e] = emb[g];
    ec[(long)o * 200 + 2 * e + 1] = cc[g];
  }
}

// ---- final 4-layer MLP head, one block per batch element ----
__global__ __launch_bounds__(256) void head_kernel(
    const float* __restrict__ cp,
    const float* __restrict__ w1, const float* __restrict__ b1,
    const float* __restrict__ w2, const float* __restrict__ b2,
    const float* __restrict__ w3, const float* __restrict__ b3,
    const float* __restrict__ w4, const float* __restrict__ b4,
    float* __restrict__ out)
{
  __shared__ float a0[400], a1[200], a2[100], a3[50];
  const int b = blockIdx.x, tid = threadIdx.x;
  for (int i = tid; i < 400; i += 256) a0[i] = cp[b * 400 + i];
  __syncthreads();
  if (tid < 200) {
    float s = b1[tid];
    const float* w = w1 + tid * 400;
    for (int k = 0; k < 400; ++k) s += a0[k] * w[k];
    a1[tid] = fmaxf(s, 0.f);
  }
  __syncthreads();
  if (tid < 100) {
    float s = b2[tid];
    const float* w = w2 + tid * 200;
    for (int k = 0; k < 200; ++k) s += a1[k] * w[k];
    a2[tid] = fmaxf(s, 0.f);
  }
  __syncthreads();
  if (tid < 50) {
    float s = b3[tid];
    const float* w = w3 + tid * 100;
    for (int k = 0; k < 100; ++k) s += a2[k] * w[k];
    a3[tid] = fmaxf(s, 0.f);
  }
  __syncthreads();
  if (tid < 5) {
    float s = b4[tid];
    const float* w = w4 + tid * 50;
    for (int k = 0; k < 50; ++k) s += a3[k] * w[k];
    out[b * 5 + tid] = s;
  }
}

extern "C" void kernel_launch(void* const* d_in, const int* in_sizes, int n_in,
                              void* d_out, int out_size, void* d_ws, size_t ws_size,
                              hipStream_t stream)
{
  const float* x    = (const float*)d_in[0];
  const float* bn_w = (const float*)d_in[1];
  const float* bn_b = (const float*)d_in[2];
  const float* pe_w = (const float*)d_in[3];
  const float* pe_b = (const float*)d_in[4];
  const float* pos  = (const float*)d_in[5];
  const float* cw1 = (const float*)d_in[6];
  const float* cb1 = (const float*)d_in[7];
  const float* cw2 = (const float*)d_in[8];
  const float* cb2 = (const float*)d_in[9];
  const float* cg  = (const float*)d_in[10];
  const float* cbe = (const float*)d_in[11];
  const float* xw1 = (const float*)d_in[12];
  const float* xb1 = (const float*)d_in[13];
  const float* xw2 = (const float*)d_in[14];
  const float* xb2 = (const float*)d_in[15];
  const float* xg  = (const float*)d_in[16];
  const float* xbe = (const float*)d_in[17];
  const float* aw1 = (const float*)d_in[18];
  const float* ab1 = (const float*)d_in[19];
  const float* aw2 = (const float*)d_in[20];
  const float* ab2 = (const float*)d_in[21];
  const float* ag  = (const float*)d_in[22];
  const float* abe = (const float*)d_in[23];
  const float* pw1 = (const float*)d_in[24];
  const float* pb1 = (const float*)d_in[25];
  const float* pw2 = (const float*)d_in[26];
  const float* pb2 = (const float*)d_in[27];
  const float* pg  = (const float*)d_in[28];
  const float* pbe = (const float*)d_in[29];
  const float* h1w = (const float*)d_in[30];
  const float* h1b = (const float*)d_in[31];
  const float* h2w = (const float*)d_in[32];
  const float* h2b = (const float*)d_in[33];
  const float* h3w = (const float*)d_in[34];
  const float* h3b = (const float*)d_in[35];
  const float* h4w = (const float*)d_in[36];
  const float* h4b = (const float*)d_in[37];

  // workspace layout (floats)
  const size_t OFF_STATS = 0;                       // 16
  const size_t OFF_PART  = 16;                      // 384 (3ch x 64 x {sum,sq})
  const size_t OFF_EMB   = 400;                     // 1024*100
  const size_t OFF_U     = OFF_EMB + 102400;        // 1024*150
  const size_t OFF_V     = OFF_U + 153600;          // 1024*150
  const size_t OFF_EC    = OFF_V + 153600;          // 1024*200
  const size_t OFF_A     = OFF_EC + 204800;         // 262144*100
  const size_t OFF_B     = OFF_A + 26214400;        // 131072*100
  const size_t NEED = (OFF_B + 13107200) * sizeof(float);
  if (ws_size < NEED) return;

  float* ws    = (float*)d_ws;
  float* stats = ws + OFF_STATS;
  float* part  = ws + OFF_PART;
  float* emb   = ws + OFF_EMB;
  float* U     = ws + OFF_U;
  float* V     = ws + OFF_V;
  float* ec    = ws + OFF_EC;
  float* A     = ws + OFF_A;
  float* B     = ws + OFF_B;

  bn_partial_kernel<<<192, 256, 0, stream>>>(x, part);
  bn_finalize_kernel<<<1, 64, 0, stream>>>(part, bn_w, bn_b, stats);
  embed_kernel<<<1024, 256, 0, stream>>>(x, stats, pe_w, pe_b, pos, emb);
  uv_kernel<<<1024, 256, 0, stream>>>(emb, cw1, U, V);
  correl_kernel<<<4096, 256, 0, stream>>>(U, V, cb1, cw2, cb2, cg, cbe, A);

  // xcorr pyramid: d 256 -> 1 (8 merge steps), rows = 1024 * half
  float* cur = A; float* nxt = B;
  int half = 128;
  for (int s = 0; s < 8; ++s) {
    int nrows = 1024 * half;
    mlp_merge_kernel<<<(nrows + RR - 1) / RR, 256, 0, stream>>>(
        cur, nxt, xw1, xb1, xw2, xb2, xg, xbe, nrows);
    float* t = cur; cur = nxt; nxt = t;
    half >>= 1;
  }
  // cc now in `cur` (== A), 1024 rows of 100

  ec_kernel<<<(102400 + 255) / 256, 256, 0, stream>>>(emb, cur, ec);
  mlp_merge_kernel<<<(1024 + RR - 1) / RR, 256, 0, stream>>>(
      ec, B, aw1, ab1, aw2, ab2, ag, abe, 1024);

  // xpath pyramid: p 256 -> 4 (6 merge steps), rows = 4 * half
  cur = B; nxt = A;
  half = 128;
  for (int s = 0; s < 6; ++s) {
    int nrows = 4 * half;
    mlp_merge_kernel<<<(nrows + RR - 1) / RR, 256, 0, stream>>>(
        cur, nxt, pw1, pb1, pw2, pb2, pg, pbe, nrows);
    float* t = cur; cur = nxt; nxt = t;
    half >>= 1;
  }
  // cp now in `cur` (== B), shape (4, 400)

  head_kernel<<<4, 256, 0, stream>>>(cur, h1w, h1b, h2w, h2b, h3w, h3b, h4w, h4b,
                                     (float*)d_out);
}